// Round 4
// baseline (18023.276 us; speedup 1.0000x reference)
//
#include <hip/hip_runtime.h>

// MGU forward, B=131072 rows, TAU=20 steps, HID=64, INPUT=1.
// 4 lanes per row: lane sub (=tid&3) owns hidden units [sub*16, sub*16+16).
// ALL per-thread state is individually-named scalar floats (macro-generated,
// literal indices only, no arrays, no helper-function pointer laundering)
// -> mem2reg promotes unconditionally, scratch is impossible by construction.
// Weights transposed in LDS, read inline as vf4 (ds_read_b128, 16-way
// broadcast per row across the wave = conflict-free).
// Cross-lane H/G broadcast via DPP quad_perm (value->value, no memory).

constexpr int BATCH = 131072;
constexpr int TAU   = 20;
constexpr int HID   = 64;
constexpr int FAN   = 65;   // INPUT + HID
constexpr int NT    = 256;  // threads per block
constexpr int LPR   = 4;    // lanes per row

typedef float vf4 __attribute__((ext_vector_type(4)));

__device__ __forceinline__ float fast_sigmoid(float a) {
    return __builtin_amdgcn_rcpf(1.0f + __expf(-a));
}
__device__ __forceinline__ float fast_tanh(float a) {
    // tanh(a) = 1 - 2/(e^{2a}+1); saturates correctly at +/-inf
    return 1.0f - 2.0f * __builtin_amdgcn_rcpf(1.0f + __expf(2.0f * a));
}

// Broadcast lane (quad_base + SRC)'s value to all 4 lanes of the quad.
template<int SRC>
__device__ __forceinline__ float quad_bcast(float v) {
    int i = __builtin_bit_cast(int, v);
    i = __builtin_amdgcn_mov_dpp(i, SRC * 0x55, 0xF, 0xF, false); // quad_perm[S,S,S,S]
    return __builtin_bit_cast(float, i);
}

#define HEXD(M) M(0) M(1) M(2) M(3) M(4) M(5) M(6) M(7) \
                M(8) M(9) M(A) M(B) M(C) M(D) M(E) M(F)

// 16 FMAs: A0..AF += w*_[..] * hk_   (wa_..wd_, hk_ from enclosing scope)
#define FMA16() \
    A0 = fmaf(wa_[0], hk_, A0); A1 = fmaf(wa_[1], hk_, A1); \
    A2 = fmaf(wa_[2], hk_, A2); A3 = fmaf(wa_[3], hk_, A3); \
    A4 = fmaf(wb_[0], hk_, A4); A5 = fmaf(wb_[1], hk_, A5); \
    A6 = fmaf(wb_[2], hk_, A6); A7 = fmaf(wb_[3], hk_, A7); \
    A8 = fmaf(wc_[0], hk_, A8); A9 = fmaf(wc_[1], hk_, A9); \
    AA = fmaf(wc_[2], hk_, AA); AB = fmaf(wc_[3], hk_, AB); \
    AC = fmaf(wd_[0], hk_, AC); AD = fmaf(wd_[1], hk_, AD); \
    AE = fmaf(wd_[2], hk_, AE); AF = fmaf(wd_[3], hk_, AF);

// One k-column: global k = q*16 + kk; source value S##kk broadcast from lane q.
#define ONEK(SW, q, kk, S) { \
    const float hk_ = quad_bcast<q>(S##kk); \
    const vf4 wa_ = *(const vf4*)&SW[1 + (q)*16 + 0x##kk][jb +  0]; \
    const vf4 wb_ = *(const vf4*)&SW[1 + (q)*16 + 0x##kk][jb +  4]; \
    const vf4 wc_ = *(const vf4*)&SW[1 + (q)*16 + 0x##kk][jb +  8]; \
    const vf4 wd_ = *(const vf4*)&SW[1 + (q)*16 + 0x##kk][jb + 12]; \
    FMA16() }

#define QUARTER(SW, q, S) \
    ONEK(SW,q,0,S) ONEK(SW,q,1,S) ONEK(SW,q,2,S) ONEK(SW,q,3,S) \
    ONEK(SW,q,4,S) ONEK(SW,q,5,S) ONEK(SW,q,6,S) ONEK(SW,q,7,S) \
    ONEK(SW,q,8,S) ONEK(SW,q,9,S) ONEK(SW,q,A,S) ONEK(SW,q,B,S) \
    ONEK(SW,q,C,S) ONEK(SW,q,D,S) ONEK(SW,q,E,S) ONEK(SW,q,F,S)

// acc init: A# = SB[jb+#] + SW[0][jb+#] * xt
#define GINIT(SW, SB) { \
    const vf4 wa_ = *(const vf4*)&SW[0][jb +  0]; \
    const vf4 wb_ = *(const vf4*)&SW[0][jb +  4]; \
    const vf4 wc_ = *(const vf4*)&SW[0][jb +  8]; \
    const vf4 wd_ = *(const vf4*)&SW[0][jb + 12]; \
    const vf4 ba_ = *(const vf4*)&SB[jb +  0]; \
    const vf4 bb_ = *(const vf4*)&SB[jb +  4]; \
    const vf4 bc_ = *(const vf4*)&SB[jb +  8]; \
    const vf4 bd_ = *(const vf4*)&SB[jb + 12]; \
    A0 = fmaf(wa_[0], xt, ba_[0]); A1 = fmaf(wa_[1], xt, ba_[1]); \
    A2 = fmaf(wa_[2], xt, ba_[2]); A3 = fmaf(wa_[3], xt, ba_[3]); \
    A4 = fmaf(wb_[0], xt, bb_[0]); A5 = fmaf(wb_[1], xt, bb_[1]); \
    A6 = fmaf(wb_[2], xt, bb_[2]); A7 = fmaf(wb_[3], xt, bb_[3]); \
    A8 = fmaf(wc_[0], xt, bc_[0]); A9 = fmaf(wc_[1], xt, bc_[1]); \
    AA = fmaf(wc_[2], xt, bc_[2]); AB = fmaf(wc_[3], xt, bc_[3]); \
    AC = fmaf(wd_[0], xt, bd_[0]); AD = fmaf(wd_[1], xt, bd_[1]); \
    AE = fmaf(wd_[2], xt, bd_[2]); AF = fmaf(wd_[3], xt, bd_[3]); }

#define GATE(SW, SB, S) \
    GINIT(SW, SB) \
    QUARTER(SW, 0, S) QUARTER(SW, 1, S) QUARTER(SW, 2, S) QUARTER(SW, 3, S)

__global__ __launch_bounds__(NT, 4) void mgu_fwd(
    const float* __restrict__ x,   // [B, TAU]
    const float* __restrict__ h0,  // [B, HID]
    const float* __restrict__ Wf,  // [HID, FAN]
    const float* __restrict__ bf,  // [HID]
    const float* __restrict__ Wc,  // [HID, FAN]
    const float* __restrict__ bc,  // [HID]
    const float* __restrict__ Wo,  // [1, HID]
    const float* __restrict__ bo,  // [1]
    float* __restrict__ out)       // [B, 1]
{
    // Transposed weights: sW*[k][j] = W*[j][k]; row = 256B, 16B-aligned.
    __shared__ float sWf[FAN][HID];
    __shared__ float sWc[FAN][HID];
    __shared__ float sbf[HID];
    __shared__ float sbc[HID];
    __shared__ float sWo[HID];

    const int tid = threadIdx.x;
    for (int i = tid; i < FAN * HID; i += NT) {
        const int k = i >> 6;        // i / HID
        const int j = i & (HID - 1); // i % HID
        sWf[k][j] = Wf[j * FAN + k];
        sWc[k][j] = Wc[j * FAN + k];
    }
    if (tid < HID) {
        sbf[tid] = bf[tid];
        sbc[tid] = bc[tid];
        sWo[tid] = Wo[tid];
    }
    __syncthreads();

    const int gt  = blockIdx.x * NT + tid;
    const int r   = gt >> 2;       // row
    const int sub = tid & 3;       // slice owner within quad
    const int jb  = sub * 16;      // this lane's j-slice base

    // State: 64 individually named scalars -> guaranteed VGPRs.
    #define DECL(d) float H##d, F##d, G##d, A##d;
    HEXD(DECL)
    #undef DECL

    // Load this lane's 16-float slice of h0 (wave-contiguous 4KB)
    {
        const vf4* hp_ = (const vf4*)(h0 + (size_t)r * HID + jb);
        const vf4 ha_ = hp_[0], hb_ = hp_[1], hc_ = hp_[2], hd_ = hp_[3];
        H0 = ha_[0]; H1 = ha_[1]; H2 = ha_[2]; H3 = ha_[3];
        H4 = hb_[0]; H5 = hb_[1]; H6 = hb_[2]; H7 = hb_[3];
        H8 = hc_[0]; H9 = hc_[1]; HA = hc_[2]; HB = hc_[3];
        HC = hd_[0]; HD = hd_[1]; HE = hd_[2]; HF = hd_[3];
    }

    const float* xr = x + (size_t)r * TAU;

    #pragma unroll 1
    for (int t = 0; t < TAU; ++t) {
        const float xt = xr[t];

        // ---- forget gate: A = bf + Wf[:,0]*xt + Wf[:,1:] . H
        GATE(sWf, sbf, H)

        // F = sigmoid(A); G = F*H; H -> P = (1-F)*H
        #define SIGE(d) F##d = fast_sigmoid(A##d);
        HEXD(SIGE)
        #undef SIGE
        #define GPE(d) G##d = F##d * H##d; H##d -= G##d;
        HEXD(GPE)
        #undef GPE

        // ---- candidate gate: A = bc + Wc[:,0]*xt + Wc[:,1:] . G
        GATE(sWc, sbc, G)

        // ---- update: H = P + F * tanh(A)
        #define UPDE(d) H##d = fmaf(F##d, fast_tanh(A##d), H##d);
        HEXD(UPDE)
        #undef UPDE
    }

    // ---- output: out[r] = bo + Wo . H  (partial per lane, reduce over quad)
    float s = 0.0f;
    {
        const vf4 w0_ = *(const vf4*)&sWo[jb +  0];
        const vf4 w1_ = *(const vf4*)&sWo[jb +  4];
        const vf4 w2_ = *(const vf4*)&sWo[jb +  8];
        const vf4 w3_ = *(const vf4*)&sWo[jb + 12];
        s = fmaf(w0_[0], H0, s); s = fmaf(w0_[1], H1, s);
        s = fmaf(w0_[2], H2, s); s = fmaf(w0_[3], H3, s);
        s = fmaf(w1_[0], H4, s); s = fmaf(w1_[1], H5, s);
        s = fmaf(w1_[2], H6, s); s = fmaf(w1_[3], H7, s);
        s = fmaf(w2_[0], H8, s); s = fmaf(w2_[1], H9, s);
        s = fmaf(w2_[2], HA, s); s = fmaf(w2_[3], HB, s);
        s = fmaf(w3_[0], HC, s); s = fmaf(w3_[1], HD, s);
        s = fmaf(w3_[2], HE, s); s = fmaf(w3_[3], HF, s);
    }
    s += __shfl_xor(s, 1, LPR);
    s += __shfl_xor(s, 2, LPR);
    if (sub == 0) out[r] = s + bo[0];
}

extern "C" void kernel_launch(void* const* d_in, const int* in_sizes, int n_in,
                              void* d_out, int out_size, void* d_ws, size_t ws_size,
                              hipStream_t stream) {
    const float* x  = (const float*)d_in[0];
    const float* h0 = (const float*)d_in[1];
    const float* Wf = (const float*)d_in[2];
    const float* bf = (const float*)d_in[3];
    const float* Wc = (const float*)d_in[4];
    const float* bc = (const float*)d_in[5];
    const float* Wo = (const float*)d_in[6];
    const float* bo = (const float*)d_in[7];
    float* out = (float*)d_out;

    dim3 grid((BATCH * LPR) / NT);   // 2048 blocks, 64 rows per block
    dim3 block(NT);
    hipLaunchKernelGGL(mgu_fwd, grid, block, 0, stream,
                       x, h0, Wf, bf, Wc, bc, Wo, bo, out);
}

// Round 5
// 1851.377 us; speedup vs baseline: 9.7351x; 9.7351x over previous
//
#include <hip/hip_runtime.h>

// MGU forward, B=131072 rows, TAU=20, HID=64, INPUT=1.
// Cooperative-block design: 64 rows per block, 256 threads.
// Thread (j = tid>>2, kq = tid&3) owns output unit j and k-slice
// [kq*16, kq*16+16). Its 32 weights + biases + x-coeffs live in NAMED
// SCALAR REGISTERS loaded once (zero per-step weight traffic, LDS or
// global). Hidden state lives in LDS tiles shared by the block:
//   Hs[64][64]  current hidden state
//   Gs[64][64]  staged F.*H (candidate-gate input)
//   Fs[64][64]  staged forget gate
// Per step: P1 partial-dot(16) -> DPP quad-reduce over kq -> sigmoid ->
// write F,G; barrier; P2 same over Gs with Wc -> tanh -> H update; barrier.
// No H double-buffer: P2's matvec reads Gs only; Hs[r][j] is read by quad j
// before quad j writes it (lockstep within warp).

constexpr int BATCH = 131072;
constexpr int TAU   = 20;
constexpr int HID   = 64;
constexpr int FAN   = 65;   // INPUT + HID
constexpr int NT    = 256;  // threads per block
constexpr int ROWS  = 64;   // rows per block

typedef float vf4 __attribute__((ext_vector_type(4)));

#define HEXD(M) M(0) M(1) M(2) M(3) M(4) M(5) M(6) M(7) \
                M(8) M(9) M(A) M(B) M(C) M(D) M(E) M(F)

__device__ __forceinline__ float fast_sigmoid(float a) {
    return __builtin_amdgcn_rcpf(1.0f + __expf(-a));
}
__device__ __forceinline__ float fast_tanh(float a) {
    // tanh(a) = 1 - 2/(e^{2a}+1); saturates correctly at +/-inf
    return 1.0f - 2.0f * __builtin_amdgcn_rcpf(1.0f + __expf(2.0f * a));
}

// Sum over the 4 lanes of each aligned quad (kq = lane&3); result in all 4.
__device__ __forceinline__ float quad_sum(float v) {
    int a = __builtin_bit_cast(int, v);
    float v1 = __builtin_bit_cast(float,
        __builtin_amdgcn_mov_dpp(a, 0xB1, 0xF, 0xF, true));  // quad_perm[1,0,3,2]
    float s1 = v + v1;
    int b = __builtin_bit_cast(int, s1);
    float v2 = __builtin_bit_cast(float,
        __builtin_amdgcn_mov_dpp(b, 0x4E, 0xF, 0xF, true));  // quad_perm[2,3,0,1]
    return s1 + v2;
}

// 4-term dot: W##a*V[0] + W##b*V[1] + W##c*V[2] + W##d*V[3]
#define CHAIN4(W,a,b,c,d,V) \
    fmaf(W##d, V[3], fmaf(W##c, V[2], fmaf(W##b, V[1], W##a * V[0])))

__global__ __launch_bounds__(NT, 3) void mgu_fwd(
    const float* __restrict__ x,   // [B, TAU]
    const float* __restrict__ h0,  // [B, HID]
    const float* __restrict__ Wf,  // [HID, FAN]
    const float* __restrict__ bf,  // [HID]
    const float* __restrict__ Wc,  // [HID, FAN]
    const float* __restrict__ bc,  // [HID]
    const float* __restrict__ Wo,  // [1, HID]
    const float* __restrict__ bo,  // [1]
    float* __restrict__ out)       // [B, 1]
{
    __shared__ alignas(16) float Hs[ROWS][HID];
    __shared__ alignas(16) float Gs[ROWS][HID];
    __shared__ alignas(16) float Fs[ROWS][HID];
    __shared__ alignas(16) float sWo[HID];

    const int tid = threadIdx.x;
    const int j   = tid >> 2;   // output unit this thread owns
    const int kq  = tid & 3;    // k-slice quarter
    const int kq16 = kq * 16;
    const int rb0 = blockIdx.x * ROWS;

    // ---- stage h0 tile (coalesced: 4096 consecutive floats)
    for (int i = tid; i < ROWS * HID; i += NT) {
        Hs[i >> 6][i & (HID - 1)] = h0[(size_t)rb0 * HID + i];
    }
    if (tid < HID) sWo[tid] = Wo[tid];

    // ---- per-thread weights into named scalar registers (one-time)
    const float fb = bf[j];
    const float cb = bc[j];
    const float fx = Wf[j * FAN];        // x-column coefficient
    const float cx = Wc[j * FAN];
    const float* wfp = Wf + j * FAN + 1 + kq16;
    const float* wcp = Wc + j * FAN + 1 + kq16;
#define LDW(d) const float fw##d = wfp[0x##d]; const float cw##d = wcp[0x##d];
    HEXD(LDW)
#undef LDW

    __syncthreads();

#define P1ROW(rr) { \
    const int r_ = (rr); \
    const float xt_ = xp[r_ * TAU]; \
    const vf4 h0_ = *(const vf4*)&Hs[r_][kq16 +  0]; \
    const vf4 h1_ = *(const vf4*)&Hs[r_][kq16 +  4]; \
    const vf4 h2_ = *(const vf4*)&Hs[r_][kq16 +  8]; \
    const vf4 h3_ = *(const vf4*)&Hs[r_][kq16 + 12]; \
    const float p0_ = CHAIN4(fw,0,1,2,3,h0_); \
    const float p1_ = CHAIN4(fw,4,5,6,7,h1_); \
    const float p2_ = CHAIN4(fw,8,9,A,B,h2_); \
    const float p3_ = CHAIN4(fw,C,D,E,F,h3_); \
    const float s_ = quad_sum((p0_ + p1_) + (p2_ + p3_)); \
    const float pre_ = fmaf(fx, xt_, fb) + s_; \
    const float f_ = fast_sigmoid(pre_); \
    const float hj_ = Hs[r_][j]; \
    if (kq == 0) { Fs[r_][j] = f_; Gs[r_][j] = f_ * hj_; } }

#define P2ROW(rr) { \
    const int r_ = (rr); \
    const float xt_ = xp[r_ * TAU]; \
    const vf4 g0_ = *(const vf4*)&Gs[r_][kq16 +  0]; \
    const vf4 g1_ = *(const vf4*)&Gs[r_][kq16 +  4]; \
    const vf4 g2_ = *(const vf4*)&Gs[r_][kq16 +  8]; \
    const vf4 g3_ = *(const vf4*)&Gs[r_][kq16 + 12]; \
    const float p0_ = CHAIN4(cw,0,1,2,3,g0_); \
    const float p1_ = CHAIN4(cw,4,5,6,7,g1_); \
    const float p2_ = CHAIN4(cw,8,9,A,B,g2_); \
    const float p3_ = CHAIN4(cw,C,D,E,F,g3_); \
    const float s_ = quad_sum((p0_ + p1_) + (p2_ + p3_)); \
    const float pre_ = fmaf(cx, xt_, cb) + s_; \
    const float cand_ = fast_tanh(pre_); \
    const float fj_ = Fs[r_][j]; \
    const float hj_ = Hs[r_][j]; \
    if (kq == 0) Hs[r_][j] = fmaf(fj_, cand_ - hj_, hj_); }

    #pragma unroll 1
    for (int t = 0; t < TAU; ++t) {
        const float* xp = x + (size_t)rb0 * TAU + t;  // xp[r*TAU] = x[rb0+r][t]

        // ---- P1: forget gate for all 64 rows
        #pragma unroll 2
        for (int r = 0; r < ROWS; ++r) { P1ROW(r) }
        __syncthreads();

        // ---- P2: candidate gate + state update for all 64 rows
        #pragma unroll 2
        for (int r = 0; r < ROWS; ++r) { P2ROW(r) }
        __syncthreads();
    }

    // ---- output: one thread per row, out[r] = bo + Wo . H[r]
    if (tid < ROWS) {
        float s = 0.0f;
        #pragma unroll
        for (int c4 = 0; c4 < HID / 4; ++c4) {
            const vf4 h = *(const vf4*)&Hs[tid][c4 * 4];
            const vf4 w = *(const vf4*)&sWo[c4 * 4];
            s = fmaf(w[0], h[0], fmaf(w[1], h[1],
                fmaf(w[2], h[2], fmaf(w[3], h[3], s))));
        }
        out[rb0 + tid] = s + bo[0];
    }
}

extern "C" void kernel_launch(void* const* d_in, const int* in_sizes, int n_in,
                              void* d_out, int out_size, void* d_ws, size_t ws_size,
                              hipStream_t stream) {
    const float* x  = (const float*)d_in[0];
    const float* h0 = (const float*)d_in[1];
    const float* Wf = (const float*)d_in[2];
    const float* bf = (const float*)d_in[3];
    const float* Wc = (const float*)d_in[4];
    const float* bc = (const float*)d_in[5];
    const float* Wo = (const float*)d_in[6];
    const float* bo = (const float*)d_in[7];
    float* out = (float*)d_out;

    dim3 grid(BATCH / ROWS);   // 2048 blocks
    dim3 block(NT);
    hipLaunchKernelGGL(mgu_fwd, grid, block, 0, stream,
                       x, h0, Wf, bf, Wc, bc, Wo, bo, out);
}

// Round 6
// 341.446 us; speedup vs baseline: 52.7851x; 5.4222x over previous
//
#include <hip/hip_runtime.h>

// MGU forward via split-bf16 MFMA. B=131072, TAU=20, HID=64, INPUT=1.
// Block = 64 rows, 256 threads = 4 waves. Wave w owns row band [w*16, w*16+16):
// 4 output tiles of 16x16 (cols 0..63) via v_mfma_f32_16x16x32_bf16.
// Precision: W and H both split hi/lo bf16; PRE = Ahi*Bhi + Alo*Bhi + Ahi*Blo
// (drops lo*lo, ~2^-16 rel). Activations/updates in fp32 registers.
// All per-step LDS state traffic is intra-wave (band-local) -> NO barriers
// in the step loop. W fragments staged once in MFMA fragment order ->
// all ds_read_b128 conflict-free.
//
// Fragment layouts (gfx950 16x16x32 bf16):
//   A: lane L holds A[row=L&15][k=(L>>4)*8+i], i=0..7
//   B: lane L holds B[k=(L>>4)*8+i][col=L&15]
//   C/D: lane L reg i holds D[row=(L>>4)*4+i][col=L&15]   (m89-verified)

constexpr int BATCH = 131072;
constexpr int TAU   = 20;
constexpr int HID   = 64;
constexpr int FAN   = 65;   // INPUT + HID
constexpr int NT    = 256;
constexpr int ROWS  = 64;

typedef float f32x4 __attribute__((ext_vector_type(4)));
typedef short s16x8 __attribute__((ext_vector_type(8)));

__device__ __forceinline__ short bf16_rne(float f) {
    unsigned u = __builtin_bit_cast(unsigned, f);
    return (short)((u + 0x7FFFu + ((u >> 16) & 1u)) >> 16);
}
__device__ __forceinline__ float bf16_up(short s) {
    return __builtin_bit_cast(float, ((unsigned)(unsigned short)s) << 16);
}
__device__ __forceinline__ float fast_sigmoid(float a) {
    return __builtin_amdgcn_rcpf(1.0f + __expf(-a));
}
__device__ __forceinline__ float fast_tanh(float a) {
    return 1.0f - 2.0f * __builtin_amdgcn_rcpf(1.0f + __expf(2.0f * a));
}

#define MFMA(A, B, C) __builtin_amdgcn_mfma_f32_16x16x32_bf16((A), (B), (C), 0, 0, 0)

__global__ __launch_bounds__(NT, 3) void mgu_fwd(
    const float* __restrict__ x,    // [B, TAU]
    const float* __restrict__ h0,   // [B, HID]
    const float* __restrict__ Wf,   // [HID, FAN]
    const float* __restrict__ bfv,  // [HID]
    const float* __restrict__ Wc,   // [HID, FAN]
    const float* __restrict__ bcv,  // [HID]
    const float* __restrict__ Wo,   // [1, HID]
    const float* __restrict__ bov,  // [1]
    float* __restrict__ out)        // [B, 1]
{
    // W fragments: [plane hi/lo][q*512 + j*8 + i], q=0..7 section,
    // element (k = (q>>2)*32 + (q&3)*8 + i, col j).
    __shared__ short sBf[2][4096];
    __shared__ short sBc[2][4096];
    // Per-wave A staging (H' then G'): [wave][plane][q*128 + c*8 + i],
    // element (row c of band, unit (q>>2)*32 + (q&3)*8 + i).
    __shared__ short sA[4][2][1024];
    __shared__ float sWo[HID];

    const int tid = threadIdx.x;

    // ---- one-time: W -> fragment-ordered hi/lo planes (RNE split)
    for (int idx = tid; idx < 4096; idx += NT) {
        const int i = idx & 7, j = (idx >> 3) & 63, q = idx >> 9;
        const int k = (q >> 2) * 32 + (q & 3) * 8 + i;
        const float wf = Wf[j * FAN + 1 + k];
        const float wc = Wc[j * FAN + 1 + k];
        const short fh = bf16_rne(wf), ch = bf16_rne(wc);
        sBf[0][idx] = fh; sBf[1][idx] = bf16_rne(wf - bf16_up(fh));
        sBc[0][idx] = ch; sBc[1][idx] = bf16_rne(wc - bf16_up(ch));
    }
    if (tid < HID) sWo[tid] = Wo[tid];
    __syncthreads();
    // ---- no further barriers: all step-loop LDS traffic is wave-private.

    const int w  = tid >> 6;
    const int L  = tid & 63;
    const int h4 = L >> 4;
    const int c0 = L & 15;
    const long rb0 = (long)blockIdx.x * ROWS;
    const int r0 = (w << 4) + (h4 << 2);      // this lane's first local row

    // tile columns + per-lane coefficients (x-column weight, biases)
    const int j0 = c0, j1 = 16 + c0, j2 = 32 + c0, j3 = 48 + c0;
    const float fb0 = bfv[j0], fb1 = bfv[j1], fb2 = bfv[j2], fb3 = bfv[j3];
    const float cb0 = bcv[j0], cb1 = bcv[j1], cb2 = bcv[j2], cb3 = bcv[j3];
    const float fx0 = Wf[j0 * FAN], fx1 = Wf[j1 * FAN], fx2 = Wf[j2 * FAN], fx3 = Wf[j3 * FAN];
    const float cx0 = Wc[j0 * FAN], cx1 = Wc[j1 * FAN], cx2 = Wc[j2 * FAN], cx3 = Wc[j3 * FAN];

    // A-staging write bases: element (T, ii) -> q_T*128 + (h4*4+ii)*8 + (c0&7)
    const int chi = c0 >> 3;
    const int wbB = h4 * 32 + (c0 & 7);
    const int wb0 = (0 + chi) * 128 + wbB;
    const int wb1 = (2 + chi) * 128 + wbB;
    const int wb2 = (4 + chi) * 128 + wbB;
    const int wb3 = (6 + chi) * 128 + wbB;
    short* const pAh = &sA[w][0][0];
    short* const pAl = &sA[w][1][0];
    const int ra0 = h4 * 128 + c0 * 8;        // a-frag read offset (ks=0); ks=1: +512

    // B-frag read offsets per (ks, T)
    const int of00 = h4 * 512 + j0 * 8,        of10 = (4 + h4) * 512 + j0 * 8;
    const int of01 = h4 * 512 + j1 * 8,        of11 = (4 + h4) * 512 + j1 * 8;
    const int of02 = h4 * 512 + j2 * 8,        of12 = (4 + h4) * 512 + j2 * 8;
    const int of03 = h4 * 512 + j3 * 8,        of13 = (4 + h4) * 512 + j3 * 8;

    // ---- H state in registers: H_T[ii] = H[r0+ii][jT]
    const float* hrow = h0 + (rb0 + r0) * HID;
    f32x4 H_0, H_1, H_2, H_3;
    H_0[0]=hrow[0*HID+j0]; H_0[1]=hrow[1*HID+j0]; H_0[2]=hrow[2*HID+j0]; H_0[3]=hrow[3*HID+j0];
    H_1[0]=hrow[0*HID+j1]; H_1[1]=hrow[1*HID+j1]; H_1[2]=hrow[2*HID+j1]; H_1[3]=hrow[3*HID+j1];
    H_2[0]=hrow[0*HID+j2]; H_2[1]=hrow[1*HID+j2]; H_2[2]=hrow[2*HID+j2]; H_2[3]=hrow[3*HID+j2];
    H_3[0]=hrow[0*HID+j3]; H_3[1]=hrow[1*HID+j3]; H_3[2]=hrow[2*HID+j3]; H_3[3]=hrow[3*HID+j3];

    const float* xp = x + (rb0 + r0) * TAU;   // rows r0..r0+3: xp[t + ii*TAU]

    // trunc-split stage of a 16-value register set into hi/lo bf16 planes
#define STAGE1(S, T, ii) { \
    const unsigned u_ = __builtin_bit_cast(unsigned, S##_##T[ii]); \
    const float lo_ = S##_##T[ii] - __builtin_bit_cast(float, u_ & 0xFFFF0000u); \
    pAh[wb##T + (ii) * 8] = (short)(u_ >> 16); \
    pAl[wb##T + (ii) * 8] = (short)(__builtin_bit_cast(unsigned, lo_) >> 16); }
#define STAGE_ALL(S) \
    STAGE1(S,0,0) STAGE1(S,0,1) STAGE1(S,0,2) STAGE1(S,0,3) \
    STAGE1(S,1,0) STAGE1(S,1,1) STAGE1(S,1,2) STAGE1(S,1,3) \
    STAGE1(S,2,0) STAGE1(S,2,1) STAGE1(S,2,2) STAGE1(S,2,3) \
    STAGE1(S,3,0) STAGE1(S,3,1) STAGE1(S,3,2) STAGE1(S,3,3)

    // 3-term split GEMM for one tile, K=64 (2 K-steps)
#define GEMM_T(CD, T, SB, AH0, AH1, AL0, AL1) { \
    const s16x8 bh0_ = *(const s16x8*)&SB[0][of0##T]; \
    const s16x8 bl0_ = *(const s16x8*)&SB[1][of0##T]; \
    const s16x8 bh1_ = *(const s16x8*)&SB[0][of1##T]; \
    const s16x8 bl1_ = *(const s16x8*)&SB[1][of1##T]; \
    CD##_##T = MFMA(AH0, bh0_, CD##_##T); \
    CD##_##T = MFMA(AL0, bh0_, CD##_##T); \
    CD##_##T = MFMA(AH0, bl0_, CD##_##T); \
    CD##_##T = MFMA(AH1, bh1_, CD##_##T); \
    CD##_##T = MFMA(AL1, bh1_, CD##_##T); \
    CD##_##T = MFMA(AH1, bl1_, CD##_##T); }

    #pragma unroll 1
    for (int t = 0; t < TAU; ++t) {
        const float x0 = xp[t], x1 = xp[t + TAU], x2 = xp[t + 2 * TAU], x3 = xp[t + 3 * TAU];

        // ---- stage H' and read A-frags
        STAGE_ALL(H)
        const s16x8 ah0 = *(const s16x8*)&pAh[ra0];
        const s16x8 ah1 = *(const s16x8*)&pAh[ra0 + 512];
        const s16x8 al0 = *(const s16x8*)&pAl[ra0];
        const s16x8 al1 = *(const s16x8*)&pAl[ra0 + 512];

        // ---- forget-gate GEMM
        f32x4 Cf_0 = {0.f,0.f,0.f,0.f}, Cf_1 = {0.f,0.f,0.f,0.f},
              Cf_2 = {0.f,0.f,0.f,0.f}, Cf_3 = {0.f,0.f,0.f,0.f};
        GEMM_T(Cf, 0, sBf, ah0, ah1, al0, al1)
        GEMM_T(Cf, 1, sBf, ah0, ah1, al0, al1)
        GEMM_T(Cf, 2, sBf, ah0, ah1, al0, al1)
        GEMM_T(Cf, 3, sBf, ah0, ah1, al0, al1)

        // ---- epilogue F: F = sigmoid(pre), G = F*H, P = H - G
        f32x4 F_0, F_1, F_2, F_3, P_0, P_1, P_2, P_3, G_0, G_1, G_2, G_3;
#define EPI_F1(T, ii, XV) { \
        const float pre_ = Cf_##T[ii] + fmaf(fx##T, XV, fb##T); \
        const float f_ = fast_sigmoid(pre_); \
        const float g_ = f_ * H_##T[ii]; \
        F_##T[ii] = f_; G_##T[ii] = g_; P_##T[ii] = H_##T[ii] - g_; }
#define EPI_F_T(T) EPI_F1(T,0,x0) EPI_F1(T,1,x1) EPI_F1(T,2,x2) EPI_F1(T,3,x3)
        EPI_F_T(0) EPI_F_T(1) EPI_F_T(2) EPI_F_T(3)
#undef EPI_F_T
#undef EPI_F1

        // ---- stage G' and read A-frags
        STAGE_ALL(G)
        const s16x8 gh0 = *(const s16x8*)&pAh[ra0];
        const s16x8 gh1 = *(const s16x8*)&pAh[ra0 + 512];
        const s16x8 gl0 = *(const s16x8*)&pAl[ra0];
        const s16x8 gl1 = *(const s16x8*)&pAl[ra0 + 512];

        // ---- candidate-gate GEMM
        f32x4 Cc_0 = {0.f,0.f,0.f,0.f}, Cc_1 = {0.f,0.f,0.f,0.f},
              Cc_2 = {0.f,0.f,0.f,0.f}, Cc_3 = {0.f,0.f,0.f,0.f};
        GEMM_T(Cc, 0, sBc, gh0, gh1, gl0, gl1)
        GEMM_T(Cc, 1, sBc, gh0, gh1, gl0, gl1)
        GEMM_T(Cc, 2, sBc, gh0, gh1, gl0, gl1)
        GEMM_T(Cc, 3, sBc, gh0, gh1, gl0, gl1)

        // ---- epilogue C: H = P + F * tanh(pre2)
#define EPI_C1(T, ii, XV) { \
        const float pre_ = Cc_##T[ii] + fmaf(cx##T, XV, cb##T); \
        H_##T[ii] = fmaf(F_##T[ii], fast_tanh(pre_), P_##T[ii]); }
#define EPI_C_T(T) EPI_C1(T,0,x0) EPI_C1(T,1,x1) EPI_C1(T,2,x2) EPI_C1(T,3,x3)
        EPI_C_T(0) EPI_C_T(1) EPI_C_T(2) EPI_C_T(3)
#undef EPI_C_T
#undef EPI_C1
    }

    // ---- output: out[r] = bo + Wo . H[r]; reduce over the 16 c0-lanes
    const float wo0 = sWo[j0], wo1 = sWo[j1], wo2 = sWo[j2], wo3 = sWo[j3];
    float s0 = fmaf(wo0, H_0[0], fmaf(wo1, H_1[0], fmaf(wo2, H_2[0], wo3 * H_3[0])));
    float s1 = fmaf(wo0, H_0[1], fmaf(wo1, H_1[1], fmaf(wo2, H_2[1], wo3 * H_3[1])));
    float s2 = fmaf(wo0, H_0[2], fmaf(wo1, H_1[2], fmaf(wo2, H_2[2], wo3 * H_3[2])));
    float s3 = fmaf(wo0, H_0[3], fmaf(wo1, H_1[3], fmaf(wo2, H_2[3], wo3 * H_3[3])));
    s0 += __shfl_xor(s0, 1, 16); s0 += __shfl_xor(s0, 2, 16);
    s0 += __shfl_xor(s0, 4, 16); s0 += __shfl_xor(s0, 8, 16);
    s1 += __shfl_xor(s1, 1, 16); s1 += __shfl_xor(s1, 2, 16);
    s1 += __shfl_xor(s1, 4, 16); s1 += __shfl_xor(s1, 8, 16);
    s2 += __shfl_xor(s2, 1, 16); s2 += __shfl_xor(s2, 2, 16);
    s2 += __shfl_xor(s2, 4, 16); s2 += __shfl_xor(s2, 8, 16);
    s3 += __shfl_xor(s3, 1, 16); s3 += __shfl_xor(s3, 2, 16);
    s3 += __shfl_xor(s3, 4, 16); s3 += __shfl_xor(s3, 8, 16);
    if (c0 == 0) {
        const float b = bov[0];
        out[rb0 + r0 + 0] = s0 + b;
        out[rb0 + r0 + 1] = s1 + b;
        out[rb0 + r0 + 2] = s2 + b;
        out[rb0 + r0 + 3] = s3 + b;
    }
}

extern "C" void kernel_launch(void* const* d_in, const int* in_sizes, int n_in,
                              void* d_out, int out_size, void* d_ws, size_t ws_size,
                              hipStream_t stream) {
    const float* x  = (const float*)d_in[0];
    const float* h0 = (const float*)d_in[1];
    const float* Wf = (const float*)d_in[2];
    const float* bf = (const float*)d_in[3];
    const float* Wc = (const float*)d_in[4];
    const float* bc = (const float*)d_in[5];
    const float* Wo = (const float*)d_in[6];
    const float* bo = (const float*)d_in[7];
    float* out = (float*)d_out;

    dim3 grid(BATCH / ROWS);   // 2048 blocks
    dim3 block(NT);
    hipLaunchKernelGGL(mgu_fwd, grid, block, 0, stream,
                       x, h0, Wf, bf, Wc, bc, Wo, bo, out);
}